// Round 2
// baseline (315.756 us; speedup 1.0000x reference)
//
#include <hip/hip_runtime.h>

// MHA: fp32 in, fp32 out. B=2, S=2048, D=1024, H=16, dk=64. bf16 MFMA internals.
// ws 16MB: Kp[0,8) Vt[8,16) -> later O32[0,16).
// d_out 16MB: Qp/ctx[0,8), WqT/WkT/WvT/WoT bf16 [8,16).
// attn: swapped QK^T (mfma(K,Q)) -> P key-contiguous per lane -> cvt_pk + b64 P writes.
// gemm: BOTH operands via global_load_lds 16B (A staged as fp32, XOR-swizzled
//       source + read, packed to bf16 at frag-load via cvt_pk), LDS dbuf,
//       1 barrier/K-step.

typedef unsigned short u16;
typedef __attribute__((ext_vector_type(8))) short bf16x8;   // MFMA A/B frag (4 VGPR)
typedef __attribute__((ext_vector_type(4))) float f32x4;    // MFMA C/D frag
typedef __attribute__((ext_vector_type(2))) unsigned int u32x2;

static __device__ __forceinline__ u16 f2bf(float x) {       // round-half-up
  union { float f; unsigned int i; } v; v.f = x;
  return (u16)((v.i + 0x8000u) >> 16);
}

static __device__ __forceinline__ unsigned int cvtpk(float lo, float hi) {
  unsigned int r;
  asm("v_cvt_pk_bf16_f32 %0, %1, %2" : "=v"(r) : "v"(lo), "v"(hi));
  return r;
}

static __device__ __forceinline__ void gload_lds16(const void* g, void* l) {
  __builtin_amdgcn_global_load_lds(
      (const __attribute__((address_space(1))) unsigned int*)g,
      (__attribute__((address_space(3))) unsigned int*)l, 16, 0, 0);
}

#define MFMA_B16(a, b, c) __builtin_amdgcn_mfma_f32_16x16x32_bf16((a), (b), (c), 0, 0, 0)

// ---------------- prep: W fp32[K][N] -> Wt bf16[N][K], 4 weights -------------
__global__ __launch_bounds__(256) void prep_w(
    const float* __restrict__ w0, const float* __restrict__ w1,
    const float* __restrict__ w2, const float* __restrict__ w3,
    u16* __restrict__ t0, u16* __restrict__ t1,
    u16* __restrict__ t2, u16* __restrict__ t3) {
  __shared__ u16 tile[64 * 68];
  const float* W; u16* T;
  switch (blockIdx.z) {
    case 0: W = w0; T = t0; break;
    case 1: W = w1; T = t1; break;
    case 2: W = w2; T = t2; break;
    default: W = w3; T = t3; break;
  }
  const int t = threadIdx.x;
  const int k0 = blockIdx.x * 64, n0 = blockIdx.y * 64;
#pragma unroll
  for (int it = 0; it < 4; ++it) {
    int idx = it * 256 + t;
    int r = idx >> 4, c4 = idx & 15;
    float4 v = *(const float4*)&W[(size_t)(k0 + r) * 1024 + n0 + c4 * 4];
    tile[r * 68 + c4 * 4 + 0] = f2bf(v.x);
    tile[r * 68 + c4 * 4 + 1] = f2bf(v.y);
    tile[r * 68 + c4 * 4 + 2] = f2bf(v.z);
    tile[r * 68 + c4 * 4 + 3] = f2bf(v.w);
  }
  __syncthreads();
#pragma unroll
  for (int it = 0; it < 2; ++it) {
    int idx = it * 256 + t;
    int n = idx >> 3, kc = idx & 7;
    bf16x8 pk;
#pragma unroll
    for (int j = 0; j < 8; ++j) pk[j] = (short)tile[(kc * 8 + j) * 68 + n];
    *(bf16x8*)&T[(size_t)(n0 + n) * 1024 + k0 + kc * 8] = pk;
  }
}

// ---------------- GEMM, tile (MT*32)x128, BK=32, dbuf LDS, 1 barrier/step ----
// AMODE==1: A fp32, staged into LDS as fp32 via global_load_lds with XOR-
//           swizzled source cols (seg^=row&7); frags packed to bf16 via cvt_pk.
// AMODE==0: A bf16 via global_load_lds, linear.
template <int MT, int AMODE, int OMODE>
__global__ __launch_bounds__(256) void gemm_bias(
    const void* a0v, const void* a1v, const void* a2v,
    const u16* __restrict__ Wt,
    const float* b0, const float* b1, const float* b2,
    void* o0, void* o1, void* o2) {
  __shared__ __align__(16) float Asf[(AMODE == 1) ? 2 * MT * 32 * 32 : 4];
  __shared__ __align__(16) u16   Asb[(AMODE == 0) ? 2 * MT * 32 * 32 : 8];
  __shared__ __align__(16) u16   Bs[2 * 128 * 32];
  const int t = threadIdx.x, wave = t >> 6, lane = t & 63;
  const int l15 = lane & 15, quad = lane >> 4;
  const int m0 = blockIdx.x * (MT * 32);
  const int n0 = blockIdx.y * 128;
  const int rg = (OMODE == 3) ? (n0 >> 10) : 0;
  const void* Av = (rg == 0) ? a0v : (rg == 1 ? a1v : a2v);
  const float* bp = (rg == 0) ? b0 : (rg == 1 ? b1 : b2);
  const int nb = (OMODE == 3) ? (n0 & 1023) : n0;
  const int wr = (wave >> 1) * (MT * 16), wc = (wave & 1) * 64;

  const f32x4 fz = {0.f, 0.f, 0.f, 0.f};
  f32x4 acc[MT][4];
#pragma unroll
  for (int mt = 0; mt < MT; ++mt)
#pragma unroll
    for (int nt = 0; nt < 4; ++nt) acc[mt][nt] = fz;

  // ---- staging helpers (all global_load_lds, linear LDS dest) ----
  // B: 128 rows x 32 bf16 = 8KB = 512 x 16B, 2/thread.
  // A fp32: MT*32 rows x 32 f32, MT*256 x 16B, MT/thread, source-XOR seg^(row&7).
  // A bf16: MT*32 rows x 32 bf16, MT*128 x 16B, MT/2 per thread.
#define STAGE(kk, bb)                                                           \
  {                                                                             \
    _Pragma("unroll")                                                           \
    for (int s = 0; s < 2; ++s) {                                               \
      int idx = s * 256 + t;                                                    \
      gload_lds16(&Wt[(size_t)(n0 + (idx >> 2)) * 1024 + (kk) + (idx & 3) * 8], \
                  &Bs[(bb) * 4096 + idx * 8]);                                  \
    }                                                                           \
    if (AMODE == 1) {                                                           \
      _Pragma("unroll")                                                         \
      for (int s = 0; s < MT; ++s) {                                            \
        int idx = s * 256 + t, row = idx >> 3, seg = idx & 7;                   \
        gload_lds16((const float*)Av + (size_t)(m0 + row) * 1024 + (kk) +       \
                        ((seg ^ (row & 7)) * 4),                                \
                    &Asf[(bb) * (MT * 32 * 32) + idx * 4]);                     \
      }                                                                         \
    } else {                                                                    \
      _Pragma("unroll")                                                         \
      for (int s = 0; s < MT / 2; ++s) {                                        \
        int idx = s * 256 + t;                                                  \
        gload_lds16((const u16*)Av + (size_t)(m0 + (idx >> 2)) * 1024 + (kk) +  \
                        (idx & 3) * 8,                                          \
                    &Asb[(bb) * (MT * 32 * 32) + idx * 8]);                     \
      }                                                                         \
    }                                                                           \
  }

  STAGE(0, 0);
  __syncthreads();

  int buf = 0;
  for (int kb = 0; kb < 1024; kb += 32) {
    const int kn = (kb + 32) & 1023;           // wrap: in-bounds, unused on last
    STAGE(kn, buf ^ 1);                        // loads stay in flight over compute
    // ---- compute from buf ----
    bf16x8 a[MT], bfr[4];
    if (AMODE == 1) {
      const int xr = l15 & 7;
#pragma unroll
      for (int mt = 0; mt < MT; ++mt) {
        const float* base = &Asf[buf * (MT * 32 * 32) + (wr + mt * 16 + l15) * 32];
        f32x4 a0 = *(const f32x4*)&base[((quad * 2) ^ xr) * 4];
        f32x4 a1 = *(const f32x4*)&base[((quad * 2 + 1) ^ xr) * 4];
        union { bf16x8 v; unsigned int w[4]; } fr;
        fr.w[0] = cvtpk(a0[0], a0[1]); fr.w[1] = cvtpk(a0[2], a0[3]);
        fr.w[2] = cvtpk(a1[0], a1[1]); fr.w[3] = cvtpk(a1[2], a1[3]);
        a[mt] = fr.v;
      }
    } else {
#pragma unroll
      for (int mt = 0; mt < MT; ++mt)
        a[mt] = *(const bf16x8*)&Asb[buf * (MT * 32 * 32) +
                                     (wr + mt * 16 + l15) * 32 + quad * 8];
    }
#pragma unroll
    for (int nt = 0; nt < 4; ++nt)
      bfr[nt] = *(const bf16x8*)&Bs[buf * 4096 + (wc + nt * 16 + l15) * 32 + quad * 8];
#pragma unroll
    for (int mt = 0; mt < MT; ++mt)
#pragma unroll
      for (int nt = 0; nt < 4; ++nt)
        acc[mt][nt] = MFMA_B16(a[mt], bfr[nt], acc[mt][nt]);
    __syncthreads();                           // drains vmcnt+lgkmcnt: buf^1 ready
    buf ^= 1;
  }
#undef STAGE

#pragma unroll
  for (int nt = 0; nt < 4; ++nt) {
    const int n = nb + wc + nt * 16 + l15;
    const float bv = bp[n];
#pragma unroll
    for (int mt = 0; mt < MT; ++mt)
#pragma unroll
      for (int r = 0; r < 4; ++r) {        // C/D: row=quad*4+r, col=l15
        const int m = m0 + wr + mt * 16 + quad * 4 + r;
        const float val = acc[mt][nt][r] + bv;
        if (OMODE == 2) {
          ((float*)o0)[(size_t)m * 1024 + n] = val;
        } else if (OMODE == 0) {
          ((u16*)o0)[(size_t)m * 1024 + n] = f2bf(val);
        } else {
          if (rg == 0)      ((u16*)o0)[(size_t)m * 1024 + n] = f2bf(val);
          else if (rg == 1) ((u16*)o1)[(size_t)m * 1024 + n] = f2bf(val);
          else {
            const int h = n >> 6, d = n & 63, bb = m >> 11, ss = m & 2047;
            ((u16*)o2)[((size_t)(bb * 16 + h) * 64 + d) * 2048 + ss] = f2bf(val);
          }
        }
      }
  }
}

// ---------------- fused attention: 128q x 128k, 8 waves, swapped QK^T --------
// mfma(K,Q): lane holds P[key=nt*16+quad*4+r][q=l15] -> key-contiguous pairs
// packed with v_cvt_pk_bf16_f32, stored to Pl[q][key] with b64 writes. Mask
// bias as f32 in LDS, read per-quad float4 (broadcast, conflict-free).
__global__ __launch_bounds__(512) void attn_fused(
    const u16* Q, const u16* __restrict__ K,
    const u16* __restrict__ Vt, const int* __restrict__ mask,
    u16* ctx) {
  __shared__ __align__(16) u16 Ks[128 * 72];      // [key][dk]   18.0 KB
  __shared__ __align__(16) u16 Vs[64 * 136];      // [d][key]    17.0 KB
  __shared__ __align__(16) u16 Pl[8][16 * 136];   // per-wave P[q][key] 34.0 KB
  __shared__ __align__(16) float Mf[2048];        // f32 bias: 0 or -inf  8.0 KB
  const int t = threadIdx.x, wave = t >> 6, lane = t & 63;
  const int l15 = lane & 15, quad = lane >> 4;
  const int bh = blockIdx.y, b = bh >> 4, h = bh & 15;
  const int q0 = blockIdx.x * 128 + wave * 16;
  const float cs = 0.125f * 1.44269504f;          // 1/sqrt(dk) * log2(e)

#pragma unroll
  for (int i = 0; i < 4; ++i) {                   // stage mask-bias once
    int idx = i * 512 + t;
    Mf[idx] = mask[b * 2048 + idx] ? -__builtin_inff() : 0.f;
  }

  const u16* Qp = Q + (size_t)(b * 2048 + q0) * 1024 + h * 64;
  const bf16x8 qf0 = *(const bf16x8*)(Qp + (size_t)l15 * 1024 + quad * 8);
  const bf16x8 qf1 = *(const bf16x8*)(Qp + (size_t)l15 * 1024 + 32 + quad * 8);

  const u16* Kbase = K + (size_t)(b * 2048) * 1024 + h * 64;   // + key*1024
  const u16* Vbase = Vt + (size_t)bh * 64 * 2048;              // + d*2048 + key

  const int kr0 = t >> 3,        kc0 = (t & 7) * 8;
  const int kr1 = (512 + t) >> 3;                     // = 64 + kr0
  const int vr0 = t >> 4,        vc0 = (t & 15) * 8;
  const int vr1 = (512 + t) >> 4;                     // = 32 + vr0

  bf16x8 gk0 = *(const bf16x8*)&Kbase[(size_t)kr0 * 1024 + kc0];
  bf16x8 gk1 = *(const bf16x8*)&Kbase[(size_t)kr1 * 1024 + kc0];
  bf16x8 gv0 = *(const bf16x8*)&Vbase[(size_t)vr0 * 2048 + vc0];
  bf16x8 gv1 = *(const bf16x8*)&Vbase[(size_t)vr1 * 2048 + vc0];

  const f32x4 fz = {0.f, 0.f, 0.f, 0.f};
  f32x4 o[4];                 // O[q=quad*4+r][d=nt*16+l15], unnormalized
  float lsum = 0.f;           // per-lane partial row-sum for q=l15
#pragma unroll
  for (int i = 0; i < 4; ++i) o[i] = fz;

  for (int kt = 0; kt < 2048; kt += 128) {
    __syncthreads();                              // prev tile fully consumed
    *(bf16x8*)&Ks[kr0 * 72 + kc0] = gk0;          // waits prefetch vmcnt here
    *(bf16x8*)&Ks[kr1 * 72 + kc0] = gk1;
    *(bf16x8*)&Vs[vr0 * 136 + vc0] = gv0;
    *(bf16x8*)&Vs[vr1 * 136 + vc0] = gv1;
    __syncthreads();
    const int kn = (kt + 128) & 2047;             // wrap: in-bounds, unused on last
    gk0 = *(const bf16x8*)&Kbase[(size_t)(kn + kr0) * 1024 + kc0];
    gk1 = *(const bf16x8*)&Kbase[(size_t)(kn + kr1) * 1024 + kc0];
    gv0 = *(const bf16x8*)&Vbase[(size_t)vr0 * 2048 + kn + vc0];
    gv1 = *(const bf16x8*)&Vbase[(size_t)vr1 * 2048 + kn + vc0];

    // S^T = (K Q^T)*scale + bias -> p = exp2;  8 key-groups of 16
#pragma unroll
    for (int nt = 0; nt < 8; ++nt) {
      const int krow = nt * 16 + l15;
      bf16x8 k0 = *(const bf16x8*)&Ks[krow * 72 + quad * 8];
      bf16x8 k1 = *(const bf16x8*)&Ks[krow * 72 + 32 + quad * 8];
      f32x4 acc = MFMA_B16(k0, qf0, fz);          // swapped: A=K rows, B=Q rows
      acc = MFMA_B16(k1, qf1, acc);
      // lane holds S[key=nt*16+quad*4+r][q=l15]; bias indexed by key
      const float4 bias4 = *(const float4*)&Mf[kt + nt * 16 + quad * 4];
      float p0 = exp2f(fmaf(acc[0], cs, bias4.x));
      float p1 = exp2f(fmaf(acc[1], cs, bias4.y));
      float p2 = exp2f(fmaf(acc[2], cs, bias4.z));
      float p3 = exp2f(fmaf(acc[3], cs, bias4.w));
      lsum += (p0 + p1) + (p2 + p3);
      u32x2 pp;
      pp.x = cvtpk(p0, p1);                       // keys quad*4+0, +1
      pp.y = cvtpk(p2, p3);                       // keys quad*4+2, +3
      *(u32x2*)&Pl[wave][l15 * 136 + nt * 16 + quad * 4] = pp;
    }
    // O += P @ V (wave-private Pl, no barrier)
#pragma unroll
    for (int kc = 0; kc < 4; ++kc) {
      const bf16x8 pf = *(const bf16x8*)&Pl[wave][l15 * 136 + kc * 32 + quad * 8];
#pragma unroll
      for (int nt = 0; nt < 4; ++nt) {
        const bf16x8 vf = *(const bf16x8*)&Vs[(nt * 16 + l15) * 136 + kc * 32 + quad * 8];
        o[nt] = MFMA_B16(pf, vf, o[nt]);
      }
    }
  }
  // row sums: reduce across quads -> every lane holds L[l15]
  lsum += __shfl_xor(lsum, 16);
  lsum += __shfl_xor(lsum, 32);
  u16* cp = ctx + (size_t)(b * 2048 + q0) * 1024 + h * 64;
#pragma unroll
  for (int r = 0; r < 4; ++r) {
    const float lrow = __shfl(lsum, quad * 4 + r);  // L[q=quad*4+r]
    const bool ok = lrow > 0.f;
    const float inv = ok ? 1.f / lrow : 0.f;
#pragma unroll
    for (int nt = 0; nt < 4; ++nt)
      cp[(quad * 4 + r) * 1024 + nt * 16 + l15] = f2bf(ok ? o[nt][r] * inv : 0.f);
  }
}

// ---------------- host launch ------------------------------------------------
extern "C" void kernel_launch(void* const* d_in, const int* in_sizes, int n_in,
                              void* d_out, int out_size, void* d_ws, size_t ws_size,
                              hipStream_t stream) {
  const float* q    = (const float*)d_in[0];
  const float* k    = (const float*)d_in[1];
  const float* v    = (const float*)d_in[2];
  const int*   mask = (const int*)d_in[3];
  const float* Wq = (const float*)d_in[4];  const float* bq = (const float*)d_in[5];
  const float* Wk = (const float*)d_in[6];  const float* bk = (const float*)d_in[7];
  const float* Wv = (const float*)d_in[8];  const float* bv = (const float*)d_in[9];
  const float* Wo = (const float*)d_in[10]; const float* bo = (const float*)d_in[11];

  char* ws = (char*)d_ws;                       // 16 MB
  u16*   Kp  = (u16*)(ws + ((size_t)0 << 20));  // [4096][1024] bf16
  u16*   Vt  = (u16*)(ws + ((size_t)8 << 20));  // [32][64][2048] bf16
  float* O32 = (float*)ws;                      // [4096][1024] fp32 (after attn)

  char* od = (char*)d_out;                      // 16 MB
  u16* ctx = (u16*)od;                          // [0,8MB): Qp then ctx in-place
  u16* WqT = (u16*)(od + ((size_t)8 << 20));
  u16* WkT = (u16*)(od + ((size_t)10 << 20));
  u16* WvT = (u16*)(od + ((size_t)12 << 20));
  u16* WoT = (u16*)(od + ((size_t)14 << 20));

  dim3 blk(256);
  prep_w<<<dim3(16, 16, 4), blk, 0, stream>>>(Wq, Wk, Wv, Wo, WqT, WkT, WvT, WoT);
  gemm_bias<4, 1, 3><<<dim3(32, 24), blk, 0, stream>>>(
      q, k, v, WqT, bq, bk, bv, (void*)ctx, (void*)Kp, (void*)Vt);
  attn_fused<<<dim3(16, 32), dim3(512), 0, stream>>>(ctx, Kp, Vt, mask, ctx);
  gemm_bias<2, 0, 2><<<dim3(64, 8), blk, 0, stream>>>(
      ctx, nullptr, nullptr, WoT, bo, nullptr, nullptr, (void*)O32, nullptr, nullptr);
  hipMemcpyAsync(d_out, O32, (size_t)out_size * sizeof(float),
                 hipMemcpyDeviceToDevice, stream);
}

// Round 3
// 263.847 us; speedup vs baseline: 1.1967x; 1.1967x over previous
//
#include <hip/hip_runtime.h>

// MHA: fp32 in, fp32 out. B=2, S=2048, D=1024, H=16, dk=64. bf16 MFMA internals.
// ws 16MB: Kp[0,8) Vt[8,16) -> later O32[0,16).
// d_out 16MB: Qp/ctx[0,8), WqT/WkT/WvT/WoT bf16 [8,16).
// GEMM: round-0 structure (reg-staged prefetch, 2 barriers/K-step) — measured best.
// attn: swapped QK^T (mfma(K,Q)) -> P key-contiguous per lane -> cvt_pk + b64
//       P writes; mask bias f32 in LDS, quad-indexed float4 broadcast.

typedef unsigned short u16;
typedef __attribute__((ext_vector_type(8))) short bf16x8;   // MFMA A/B frag (4 VGPR)
typedef __attribute__((ext_vector_type(4))) float f32x4;    // MFMA C/D frag
typedef __attribute__((ext_vector_type(2))) unsigned int u32x2;

static __device__ __forceinline__ u16 f2bf(float x) {       // round-half-up
  union { float f; unsigned int i; } v; v.f = x;
  return (u16)((v.i + 0x8000u) >> 16);
}
static __device__ __forceinline__ float bf2f(u16 u) {
  union { unsigned int i; float f; } v; v.i = ((unsigned int)u) << 16; return v.f;
}

static __device__ __forceinline__ unsigned int cvtpk(float lo, float hi) {
  unsigned int r;
  asm("v_cvt_pk_bf16_f32 %0, %1, %2" : "=v"(r) : "v"(lo), "v"(hi));
  return r;
}

#define MFMA_B16(a, b, c) __builtin_amdgcn_mfma_f32_16x16x32_bf16((a), (b), (c), 0, 0, 0)

// ---------------- prep: W fp32[K][N] -> Wt bf16[N][K], 4 weights -------------
__global__ __launch_bounds__(256) void prep_w(
    const float* __restrict__ w0, const float* __restrict__ w1,
    const float* __restrict__ w2, const float* __restrict__ w3,
    u16* __restrict__ t0, u16* __restrict__ t1,
    u16* __restrict__ t2, u16* __restrict__ t3) {
  __shared__ u16 tile[64 * 68];
  const float* W; u16* T;
  switch (blockIdx.z) {
    case 0: W = w0; T = t0; break;
    case 1: W = w1; T = t1; break;
    case 2: W = w2; T = t2; break;
    default: W = w3; T = t3; break;
  }
  const int t = threadIdx.x;
  const int k0 = blockIdx.x * 64, n0 = blockIdx.y * 64;
#pragma unroll
  for (int it = 0; it < 4; ++it) {
    int idx = it * 256 + t;
    int r = idx >> 4, c4 = idx & 15;
    float4 v = *(const float4*)&W[(size_t)(k0 + r) * 1024 + n0 + c4 * 4];
    tile[r * 68 + c4 * 4 + 0] = f2bf(v.x);
    tile[r * 68 + c4 * 4 + 1] = f2bf(v.y);
    tile[r * 68 + c4 * 4 + 2] = f2bf(v.z);
    tile[r * 68 + c4 * 4 + 3] = f2bf(v.w);
  }
  __syncthreads();
#pragma unroll
  for (int it = 0; it < 2; ++it) {
    int idx = it * 256 + t;
    int n = idx >> 3, kc = idx & 7;
    bf16x8 pk;
#pragma unroll
    for (int j = 0; j < 8; ++j) pk[j] = (short)tile[(kc * 8 + j) * 68 + n];
    *(bf16x8*)&T[(size_t)(n0 + n) * 1024 + k0 + kc * 8] = pk;
  }
}

// ---------------- GEMM, tile (MT*32)x128, BK=32, reg-staged prefetch ---------
template <int MT, int AMODE, int OMODE>
__global__ __launch_bounds__(256) void gemm_bias(
    const void* a0v, const void* a1v, const void* a2v,
    const u16* __restrict__ Wt,
    const float* b0, const float* b1, const float* b2,
    void* o0, void* o1, void* o2) {
  __shared__ __align__(16) u16 As[MT * 32 * 32];
  __shared__ __align__(16) u16 Bs[128 * 32];
  const int t = threadIdx.x, wave = t >> 6, lane = t & 63;
  const int l15 = lane & 15, quad = lane >> 4;
  const int m0 = blockIdx.x * (MT * 32);
  const int n0 = blockIdx.y * 128;
  const int rg = (OMODE == 3) ? (n0 >> 10) : 0;
  const void* Av = (rg == 0) ? a0v : (rg == 1 ? a1v : a2v);
  const float* bp = (rg == 0) ? b0 : (rg == 1 ? b1 : b2);
  const int nb = (OMODE == 3) ? (n0 & 1023) : n0;
  const int wr = (wave >> 1) * (MT * 16), wc = (wave & 1) * 64;

  const f32x4 fz = {0.f, 0.f, 0.f, 0.f};
  f32x4 acc[MT][4];
#pragma unroll
  for (int mt = 0; mt < MT; ++mt)
#pragma unroll
    for (int nt = 0; nt < 4; ++nt) acc[mt][nt] = fz;

  float4 pa[MT / 2][2]; bf16x8 pab[MT / 2]; bf16x8 pb[2];
#pragma unroll
  for (int s = 0; s < MT / 2; ++s) {
    int idx = s * 256 + t, row = idx >> 2, seg = idx & 3;
    if (AMODE == 1) {
      const float* ap = (const float*)Av + (size_t)(m0 + row) * 1024 + seg * 8;
      pa[s][0] = *(const float4*)ap; pa[s][1] = *(const float4*)(ap + 4);
    } else {
      pab[s] = *(const bf16x8*)((const u16*)Av + (size_t)(m0 + row) * 1024 + seg * 8);
    }
  }
#pragma unroll
  for (int s = 0; s < 2; ++s) {
    int idx = s * 256 + t, row = idx >> 2, seg = idx & 3;
    pb[s] = *(const bf16x8*)&Wt[(size_t)(n0 + row) * 1024 + seg * 8];
  }

  for (int kb = 0; kb < 1024; kb += 32) {
    __syncthreads();
#pragma unroll
    for (int s = 0; s < MT / 2; ++s) {
      int idx = s * 256 + t, row = idx >> 2, seg = idx & 3;
      bf16x8 pk;
      if (AMODE == 1) {
        pk[0] = (short)f2bf(pa[s][0].x); pk[1] = (short)f2bf(pa[s][0].y);
        pk[2] = (short)f2bf(pa[s][0].z); pk[3] = (short)f2bf(pa[s][0].w);
        pk[4] = (short)f2bf(pa[s][1].x); pk[5] = (short)f2bf(pa[s][1].y);
        pk[6] = (short)f2bf(pa[s][1].z); pk[7] = (short)f2bf(pa[s][1].w);
      } else pk = pab[s];
      *(bf16x8*)&As[row * 32 + seg * 8] = pk;
    }
#pragma unroll
    for (int s = 0; s < 2; ++s) {
      int idx = s * 256 + t, row = idx >> 2, seg = idx & 3;
      *(bf16x8*)&Bs[row * 32 + seg * 8] = pb[s];
    }
    __syncthreads();
    const int kn = (kb + 32) & 1023;
#pragma unroll
    for (int s = 0; s < MT / 2; ++s) {
      int idx = s * 256 + t, row = idx >> 2, seg = idx & 3;
      if (AMODE == 1) {
        const float* ap = (const float*)Av + (size_t)(m0 + row) * 1024 + kn + seg * 8;
        pa[s][0] = *(const float4*)ap; pa[s][1] = *(const float4*)(ap + 4);
      } else {
        pab[s] = *(const bf16x8*)((const u16*)Av + (size_t)(m0 + row) * 1024 + kn + seg * 8);
      }
    }
#pragma unroll
    for (int s = 0; s < 2; ++s) {
      int idx = s * 256 + t, row = idx >> 2, seg = idx & 3;
      pb[s] = *(const bf16x8*)&Wt[(size_t)(n0 + row) * 1024 + kn + seg * 8];
    }
    bf16x8 a[MT], bfr[4];
#pragma unroll
    for (int mt = 0; mt < MT; ++mt)
      a[mt] = *(const bf16x8*)&As[(wr + mt * 16 + l15) * 32 + quad * 8];
#pragma unroll
    for (int nt = 0; nt < 4; ++nt)
      bfr[nt] = *(const bf16x8*)&Bs[(wc + nt * 16 + l15) * 32 + quad * 8];
#pragma unroll
    for (int mt = 0; mt < MT; ++mt)
#pragma unroll
      for (int nt = 0; nt < 4; ++nt)
        acc[mt][nt] = MFMA_B16(a[mt], bfr[nt], acc[mt][nt]);
  }

#pragma unroll
  for (int nt = 0; nt < 4; ++nt) {
    const int n = nb + wc + nt * 16 + l15;
    const float bv = bp[n];
#pragma unroll
    for (int mt = 0; mt < MT; ++mt)
#pragma unroll
      for (int r = 0; r < 4; ++r) {        // C/D: row=quad*4+r, col=l15
        const int m = m0 + wr + mt * 16 + quad * 4 + r;
        const float val = acc[mt][nt][r] + bv;
        if (OMODE == 2) {
          ((float*)o0)[(size_t)m * 1024 + n] = val;
        } else if (OMODE == 0) {
          ((u16*)o0)[(size_t)m * 1024 + n] = f2bf(val);
        } else {
          if (rg == 0)      ((u16*)o0)[(size_t)m * 1024 + n] = f2bf(val);
          else if (rg == 1) ((u16*)o1)[(size_t)m * 1024 + n] = f2bf(val);
          else {
            const int h = n >> 6, d = n & 63, bb = m >> 11, ss = m & 2047;
            ((u16*)o2)[((size_t)(bb * 16 + h) * 64 + d) * 2048 + ss] = f2bf(val);
          }
        }
      }
  }
}

// ---------------- fused attention: 128q x 128k, 8 waves, swapped QK^T --------
// mfma(K,Q): lane holds P[key=nt*16+quad*4+r][q=l15] -> key-contiguous pairs
// packed with v_cvt_pk_bf16_f32, stored to Pl[q][key] with b64 writes. Mask
// bias as f32 in LDS, read per-quad float4 (broadcast, conflict-free).
__global__ __launch_bounds__(512) void attn_fused(
    const u16* Q, const u16* __restrict__ K,
    const u16* __restrict__ Vt, const int* __restrict__ mask,
    u16* ctx) {
  __shared__ __align__(16) u16 Ks[128 * 72];      // [key][dk]   18.0 KB
  __shared__ __align__(16) u16 Vs[64 * 136];      // [d][key]    17.0 KB
  __shared__ __align__(16) u16 Pl[8][16 * 136];   // per-wave P[q][key] 34.0 KB
  __shared__ __align__(16) float Mf[2048];        // f32 bias: 0 or -inf  8.0 KB
  const int t = threadIdx.x, wave = t >> 6, lane = t & 63;
  const int l15 = lane & 15, quad = lane >> 4;
  const int bh = blockIdx.y, b = bh >> 4, h = bh & 15;
  const int q0 = blockIdx.x * 128 + wave * 16;
  const float cs = 0.125f * 1.44269504f;          // 1/sqrt(dk) * log2(e)

#pragma unroll
  for (int i = 0; i < 4; ++i) {                   // stage mask-bias once
    int idx = i * 512 + t;
    Mf[idx] = mask[b * 2048 + idx] ? -__builtin_inff() : 0.f;
  }

  const u16* Qp = Q + (size_t)(b * 2048 + q0) * 1024 + h * 64;
  const bf16x8 qf0 = *(const bf16x8*)(Qp + (size_t)l15 * 1024 + quad * 8);
  const bf16x8 qf1 = *(const bf16x8*)(Qp + (size_t)l15 * 1024 + 32 + quad * 8);

  const u16* Kbase = K + (size_t)(b * 2048) * 1024 + h * 64;   // + key*1024
  const u16* Vbase = Vt + (size_t)bh * 64 * 2048;              // + d*2048 + key

  const int kr0 = t >> 3,        kc0 = (t & 7) * 8;
  const int kr1 = (512 + t) >> 3;                     // = 64 + kr0
  const int vr0 = t >> 4,        vc0 = (t & 15) * 8;
  const int vr1 = (512 + t) >> 4;                     // = 32 + vr0

  bf16x8 gk0 = *(const bf16x8*)&Kbase[(size_t)kr0 * 1024 + kc0];
  bf16x8 gk1 = *(const bf16x8*)&Kbase[(size_t)kr1 * 1024 + kc0];
  bf16x8 gv0 = *(const bf16x8*)&Vbase[(size_t)vr0 * 2048 + vc0];
  bf16x8 gv1 = *(const bf16x8*)&Vbase[(size_t)vr1 * 2048 + vc0];

  const f32x4 fz = {0.f, 0.f, 0.f, 0.f};
  f32x4 o[4];                 // O[q=quad*4+r][d=nt*16+l15], unnormalized
  float lsum = 0.f;           // per-lane partial row-sum for q=l15
#pragma unroll
  for (int i = 0; i < 4; ++i) o[i] = fz;

  for (int kt = 0; kt < 2048; kt += 128) {
    __syncthreads();                              // prev tile fully consumed
    *(bf16x8*)&Ks[kr0 * 72 + kc0] = gk0;          // waits prefetch vmcnt here
    *(bf16x8*)&Ks[kr1 * 72 + kc0] = gk1;
    *(bf16x8*)&Vs[vr0 * 136 + vc0] = gv0;
    *(bf16x8*)&Vs[vr1 * 136 + vc0] = gv1;
    __syncthreads();
    const int kn = (kt + 128) & 2047;             // wrap: in-bounds, unused on last
    gk0 = *(const bf16x8*)&Kbase[(size_t)(kn + kr0) * 1024 + kc0];
    gk1 = *(const bf16x8*)&Kbase[(size_t)(kn + kr1) * 1024 + kc0];
    gv0 = *(const bf16x8*)&Vbase[(size_t)vr0 * 2048 + kn + vc0];
    gv1 = *(const bf16x8*)&Vbase[(size_t)vr1 * 2048 + kn + vc0];

    // S^T = (K Q^T)*scale + bias -> p = exp2;  8 key-groups of 16
#pragma unroll
    for (int nt = 0; nt < 8; ++nt) {
      const int krow = nt * 16 + l15;
      bf16x8 k0 = *(const bf16x8*)&Ks[krow * 72 + quad * 8];
      bf16x8 k1 = *(const bf16x8*)&Ks[krow * 72 + 32 + quad * 8];
      f32x4 acc = MFMA_B16(k0, qf0, fz);          // swapped: A=K rows, B=Q rows
      acc = MFMA_B16(k1, qf1, acc);
      // lane holds S[key=nt*16+quad*4+r][q=l15]; bias indexed by key
      const float4 bias4 = *(const float4*)&Mf[kt + nt * 16 + quad * 4];
      float p0 = exp2f(fmaf(acc[0], cs, bias4.x));
      float p1 = exp2f(fmaf(acc[1], cs, bias4.y));
      float p2 = exp2f(fmaf(acc[2], cs, bias4.z));
      float p3 = exp2f(fmaf(acc[3], cs, bias4.w));
      lsum += (p0 + p1) + (p2 + p3);
      u32x2 pp;
      pp.x = cvtpk(p0, p1);                       // keys quad*4+0, +1
      pp.y = cvtpk(p2, p3);                       // keys quad*4+2, +3
      *(u32x2*)&Pl[wave][l15 * 136 + nt * 16 + quad * 4] = pp;
    }
    // O += P @ V (wave-private Pl, no barrier)
#pragma unroll
    for (int kc = 0; kc < 4; ++kc) {
      const bf16x8 pf = *(const bf16x8*)&Pl[wave][l15 * 136 + kc * 32 + quad * 8];
#pragma unroll
      for (int nt = 0; nt < 4; ++nt) {
        const bf16x8 vf = *(const bf16x8*)&Vs[(nt * 16 + l15) * 136 + kc * 32 + quad * 8];
        o[nt] = MFMA_B16(pf, vf, o[nt]);
      }
    }
  }
  // row sums: reduce across quads -> every lane holds L[l15]
  lsum += __shfl_xor(lsum, 16);
  lsum += __shfl_xor(lsum, 32);
  u16* cp = ctx + (size_t)(b * 2048 + q0) * 1024 + h * 64;
#pragma unroll
  for (int r = 0; r < 4; ++r) {
    const float lrow = __shfl(lsum, quad * 4 + r);  // L[q=quad*4+r]
    const bool ok = lrow > 0.f;
    const float inv = ok ? 1.f / lrow : 0.f;
#pragma unroll
    for (int nt = 0; nt < 4; ++nt)
      cp[(quad * 4 + r) * 1024 + nt * 16 + l15] = f2bf(ok ? o[nt][r] * inv : 0.f);
  }
}

// ---------------- host launch ------------------------------------------------
extern "C" void kernel_launch(void* const* d_in, const int* in_sizes, int n_in,
                              void* d_out, int out_size, void* d_ws, size_t ws_size,
                              hipStream_t stream) {
  const float* q    = (const float*)d_in[0];
  const float* k    = (const float*)d_in[1];
  const float* v    = (const float*)d_in[2];
  const int*   mask = (const int*)d_in[3];
  const float* Wq = (const float*)d_in[4];  const float* bq = (const float*)d_in[5];
  const float* Wk = (const float*)d_in[6];  const float* bk = (const float*)d_in[7];
  const float* Wv = (const float*)d_in[8];  const float* bv = (const float*)d_in[9];
  const float* Wo = (const float*)d_in[10]; const float* bo = (const float*)d_in[11];

  char* ws = (char*)d_ws;                       // 16 MB
  u16*   Kp  = (u16*)(ws + ((size_t)0 << 20));  // [4096][1024] bf16
  u16*   Vt  = (u16*)(ws + ((size_t)8 << 20));  // [32][64][2048] bf16
  float* O32 = (float*)ws;                      // [4096][1024] fp32 (after attn)

  char* od = (char*)d_out;                      // 16 MB
  u16* ctx = (u16*)od;                          // [0,8MB): Qp then ctx in-place
  u16* WqT = (u16*)(od + ((size_t)8 << 20));
  u16* WkT = (u16*)(od + ((size_t)10 << 20));
  u16* WvT = (u16*)(od + ((size_t)12 << 20));
  u16* WoT = (u16*)(od + ((size_t)14 << 20));

  dim3 blk(256);
  prep_w<<<dim3(16, 16, 4), blk, 0, stream>>>(Wq, Wk, Wv, Wo, WqT, WkT, WvT, WoT);
  gemm_bias<4, 1, 3><<<dim3(32, 24), blk, 0, stream>>>(
      q, k, v, WqT, bq, bk, bv, (void*)ctx, (void*)Kp, (void*)Vt);
  attn_fused<<<dim3(16, 32), dim3(512), 0, stream>>>(ctx, Kp, Vt, mask, ctx);
  gemm_bias<2, 0, 2><<<dim3(64, 8), blk, 0, stream>>>(
      ctx, nullptr, nullptr, WoT, bo, nullptr, nullptr, (void*)O32, nullptr, nullptr);
  hipMemcpyAsync(d_out, O32, (size_t)out_size * sizeof(float),
                 hipMemcpyDeviceToDevice, stream);
}

// Round 4
// 250.322 us; speedup vs baseline: 1.2614x; 1.0540x over previous
//
#include <hip/hip_runtime.h>

// MHA: fp32 in, fp32 out. B=2, S=2048, D=1024, H=16, dk=64. bf16 MFMA internals.
// ws 16MB: Kp[0,8) Vt[8,16) -> later O32[0,16).
// d_out 16MB: Qp/ctx[0,8), WqT/WkT/WvT/WoT bf16 [8,16).
// GEMM: round-0 structure + prefetch distance 2 (ping-pong reg sets, 2x unroll).
// attn: swapped QK^T; compact XOR-swizzled LDS (Ks[128][64], Vs[64][128],
//       Pl[16][64]/wave with split-PV halves); per-tile mask bias Mf[128].

typedef unsigned short u16;
typedef __attribute__((ext_vector_type(8))) short bf16x8;   // MFMA A/B frag (4 VGPR)
typedef __attribute__((ext_vector_type(4))) float f32x4;    // MFMA C/D frag
typedef __attribute__((ext_vector_type(2))) unsigned int u32x2;

static __device__ __forceinline__ u16 f2bf(float x) {       // round-half-up
  union { float f; unsigned int i; } v; v.f = x;
  return (u16)((v.i + 0x8000u) >> 16);
}

static __device__ __forceinline__ unsigned int cvtpk(float lo, float hi) {
  unsigned int r;
  asm("v_cvt_pk_bf16_f32 %0, %1, %2" : "=v"(r) : "v"(lo), "v"(hi));
  return r;
}

#define MFMA_B16(a, b, c) __builtin_amdgcn_mfma_f32_16x16x32_bf16((a), (b), (c), 0, 0, 0)

// ---------------- prep: W fp32[K][N] -> Wt bf16[N][K], 4 weights -------------
__global__ __launch_bounds__(256) void prep_w(
    const float* __restrict__ w0, const float* __restrict__ w1,
    const float* __restrict__ w2, const float* __restrict__ w3,
    u16* __restrict__ t0, u16* __restrict__ t1,
    u16* __restrict__ t2, u16* __restrict__ t3) {
  __shared__ u16 tile[64 * 68];
  const float* W; u16* T;
  switch (blockIdx.z) {
    case 0: W = w0; T = t0; break;
    case 1: W = w1; T = t1; break;
    case 2: W = w2; T = t2; break;
    default: W = w3; T = t3; break;
  }
  const int t = threadIdx.x;
  const int k0 = blockIdx.x * 64, n0 = blockIdx.y * 64;
#pragma unroll
  for (int it = 0; it < 4; ++it) {
    int idx = it * 256 + t;
    int r = idx >> 4, c4 = idx & 15;
    float4 v = *(const float4*)&W[(size_t)(k0 + r) * 1024 + n0 + c4 * 4];
    tile[r * 68 + c4 * 4 + 0] = f2bf(v.x);
    tile[r * 68 + c4 * 4 + 1] = f2bf(v.y);
    tile[r * 68 + c4 * 4 + 2] = f2bf(v.z);
    tile[r * 68 + c4 * 4 + 3] = f2bf(v.w);
  }
  __syncthreads();
#pragma unroll
  for (int it = 0; it < 2; ++it) {
    int idx = it * 256 + t;
    int n = idx >> 3, kc = idx & 7;
    bf16x8 pk;
#pragma unroll
    for (int j = 0; j < 8; ++j) pk[j] = (short)tile[(kc * 8 + j) * 68 + n];
    *(bf16x8*)&T[(size_t)(n0 + n) * 1024 + k0 + kc * 8] = pk;
  }
}

// ---------------- GEMM, tile (MT*32)x128, BK=32, prefetch distance 2 ---------
template <int MT, int AMODE, int OMODE>
__global__ __launch_bounds__(256) void gemm_bias(
    const void* a0v, const void* a1v, const void* a2v,
    const u16* __restrict__ Wt,
    const float* b0, const float* b1, const float* b2,
    void* o0, void* o1, void* o2) {
  __shared__ __align__(16) u16 As[MT * 32 * 32];
  __shared__ __align__(16) u16 Bs[128 * 32];
  const int t = threadIdx.x, wave = t >> 6, lane = t & 63;
  const int l15 = lane & 15, quad = lane >> 4;
  const int m0 = blockIdx.x * (MT * 32);
  const int n0 = blockIdx.y * 128;
  const int rg = (OMODE == 3) ? (n0 >> 10) : 0;
  const void* Av = (rg == 0) ? a0v : (rg == 1 ? a1v : a2v);
  const float* bp = (rg == 0) ? b0 : (rg == 1 ? b1 : b2);
  const int nb = (OMODE == 3) ? (n0 & 1023) : n0;
  const int wr = (wave >> 1) * (MT * 16), wc = (wave & 1) * 64;

  const f32x4 fz = {0.f, 0.f, 0.f, 0.f};
  f32x4 acc[MT][4];
#pragma unroll
  for (int mt = 0; mt < MT; ++mt)
#pragma unroll
    for (int nt = 0; nt < 4; ++nt) acc[mt][nt] = fz;

  float4 paA[MT / 2][2], paB[MT / 2][2];
  bf16x8 pabA[MT / 2], pabB[MT / 2];
  bf16x8 pbA[2], pbB[2];

#define GLOAD_A(pa_, pab_, kk)                                                  \
  _Pragma("unroll")                                                             \
  for (int s = 0; s < MT / 2; ++s) {                                            \
    int idx = s * 256 + t, row = idx >> 2, seg = idx & 3;                       \
    if (AMODE == 1) {                                                           \
      const float* ap = (const float*)Av + (size_t)(m0 + row) * 1024 + (kk) + seg * 8; \
      pa_[s][0] = *(const float4*)ap; pa_[s][1] = *(const float4*)(ap + 4);     \
    } else {                                                                    \
      pab_[s] = *(const bf16x8*)((const u16*)Av + (size_t)(m0 + row) * 1024 + (kk) + seg * 8); \
    }                                                                           \
  }
#define GLOAD_B(pb_, kk)                                                        \
  _Pragma("unroll")                                                             \
  for (int s = 0; s < 2; ++s) {                                                 \
    int idx = s * 256 + t, row = idx >> 2, seg = idx & 3;                       \
    pb_[s] = *(const bf16x8*)&Wt[(size_t)(n0 + row) * 1024 + (kk) + seg * 8];   \
  }
#define STORE_LDS(pa_, pab_, pb_)                                               \
  _Pragma("unroll")                                                             \
  for (int s = 0; s < MT / 2; ++s) {                                            \
    int idx = s * 256 + t, row = idx >> 2, seg = idx & 3;                       \
    bf16x8 pk;                                                                  \
    if (AMODE == 1) {                                                           \
      pk[0] = (short)f2bf(pa_[s][0].x); pk[1] = (short)f2bf(pa_[s][0].y);       \
      pk[2] = (short)f2bf(pa_[s][0].z); pk[3] = (short)f2bf(pa_[s][0].w);       \
      pk[4] = (short)f2bf(pa_[s][1].x); pk[5] = (short)f2bf(pa_[s][1].y);       \
      pk[6] = (short)f2bf(pa_[s][1].z); pk[7] = (short)f2bf(pa_[s][1].w);       \
    } else pk = pab_[s];                                                        \
    *(bf16x8*)&As[row * 32 + seg * 8] = pk;                                     \
  }                                                                             \
  _Pragma("unroll")                                                             \
  for (int s = 0; s < 2; ++s) {                                                 \
    int idx = s * 256 + t, row = idx >> 2, seg = idx & 3;                       \
    *(bf16x8*)&Bs[row * 32 + seg * 8] = pb_[s];                                 \
  }
#define COMPUTE_TILE()                                                          \
  {                                                                             \
    bf16x8 a[MT], bfr[4];                                                       \
    _Pragma("unroll")                                                           \
    for (int mt = 0; mt < MT; ++mt)                                             \
      a[mt] = *(const bf16x8*)&As[(wr + mt * 16 + l15) * 32 + quad * 8];        \
    _Pragma("unroll")                                                           \
    for (int nt = 0; nt < 4; ++nt)                                              \
      bfr[nt] = *(const bf16x8*)&Bs[(wc + nt * 16 + l15) * 32 + quad * 8];      \
    _Pragma("unroll")                                                           \
    for (int mt = 0; mt < MT; ++mt)                                             \
      _Pragma("unroll")                                                         \
      for (int nt = 0; nt < 4; ++nt)                                            \
        acc[mt][nt] = MFMA_B16(a[mt], bfr[nt], acc[mt][nt]);                    \
  }

  GLOAD_A(paA, pabA, 0); GLOAD_B(pbA, 0);
  GLOAD_A(paB, pabB, 32); GLOAD_B(pbB, 32);

  for (int kb = 0; kb < 1024; kb += 64) {
    // half 1: tile kb from reg set A; reload A with kb+64 (distance 2)
    __syncthreads();
    STORE_LDS(paA, pabA, pbA);
    __syncthreads();
    {
      const int kn = (kb + 64) & 1023;           // wrap: in-bounds, unused on last
      GLOAD_A(paA, pabA, kn); GLOAD_B(pbA, kn);
    }
    COMPUTE_TILE();
    // half 2: tile kb+32 from reg set B; reload B with kb+96
    __syncthreads();
    STORE_LDS(paB, pabB, pbB);
    __syncthreads();
    {
      const int kn = (kb + 96) & 1023;
      GLOAD_A(paB, pabB, kn); GLOAD_B(pbB, kn);
    }
    COMPUTE_TILE();
  }
#undef GLOAD_A
#undef GLOAD_B
#undef STORE_LDS
#undef COMPUTE_TILE

#pragma unroll
  for (int nt = 0; nt < 4; ++nt) {
    const int n = nb + wc + nt * 16 + l15;
    const float bv = bp[n];
#pragma unroll
    for (int mt = 0; mt < MT; ++mt)
#pragma unroll
      for (int r = 0; r < 4; ++r) {        // C/D: row=quad*4+r, col=l15
        const int m = m0 + wr + mt * 16 + quad * 4 + r;
        const float val = acc[mt][nt][r] + bv;
        if (OMODE == 2) {
          ((float*)o0)[(size_t)m * 1024 + n] = val;
        } else if (OMODE == 0) {
          ((u16*)o0)[(size_t)m * 1024 + n] = f2bf(val);
        } else {
          if (rg == 0)      ((u16*)o0)[(size_t)m * 1024 + n] = f2bf(val);
          else if (rg == 1) ((u16*)o1)[(size_t)m * 1024 + n] = f2bf(val);
          else {
            const int h = n >> 6, d = n & 63, bb = m >> 11, ss = m & 2047;
            ((u16*)o2)[((size_t)(bb * 16 + h) * 64 + d) * 2048 + ss] = f2bf(val);
          }
        }
      }
  }
}

// ---------------- fused attention: 128q x 128k, 8 waves, swapped QK^T --------
// Compact XOR-swizzled LDS (u16 idx ^= (row&7)<<3; all rows keyed by l15&7 on
// the read side, own row on the write side — reg-staged ds_write both ways).
// PV split into two 64-key half-phases so Pl is [16][64] per wave (wave-
// private, no barriers). Mask bias staged per-tile into Mf[128] alongside the
// K/V register prefetch.
__global__ __launch_bounds__(512) void attn_fused(
    const u16* Q, const u16* __restrict__ K,
    const u16* __restrict__ Vt, const int* __restrict__ mask,
    u16* ctx) {
  __shared__ __align__(16) u16 Ks[128 * 64];      // [key][dk]  16 KB, swizzled
  __shared__ __align__(16) u16 Vs[64 * 128];      // [d][key]   16 KB, swizzled
  __shared__ __align__(16) u16 Pl[8][16 * 64];    // per-wave P half-tile, 16 KB
  __shared__ __align__(16) float Mf[128];         // current-tile bias 0/-inf
  const int t = threadIdx.x, wave = t >> 6, lane = t & 63;
  const int l15 = lane & 15, quad = lane >> 4;
  const int bh = blockIdx.y, b = bh >> 4, h = bh & 15;
  const int q0 = blockIdx.x * 128 + wave * 16;
  const float cs = 0.125f * 1.44269504f;          // 1/sqrt(dk) * log2(e)
  const int swz = (l15 & 7) << 3;                 // read-side XOR (u16 units)

  const u16* Qp = Q + (size_t)(b * 2048 + q0) * 1024 + h * 64;
  const bf16x8 qf0 = *(const bf16x8*)(Qp + (size_t)l15 * 1024 + quad * 8);
  const bf16x8 qf1 = *(const bf16x8*)(Qp + (size_t)l15 * 1024 + 32 + quad * 8);

  const u16* Kbase = K + (size_t)(b * 2048) * 1024 + h * 64;   // + key*1024
  const u16* Vbase = Vt + (size_t)bh * 64 * 2048;              // + d*2048 + key

  // staging maps (512 threads):
  const int kr0 = t >> 3,  kc0 = (t & 7) * 8;     // K: 128 x 64
  const int kr1 = 64 + kr0;
  const int vr0 = t >> 4,  vc0 = (t & 15) * 8;    // V: 64 x 128
  const int vr1 = 32 + vr0;
  const int ksw0 = (kr0 * 64 + kc0) ^ ((kr0 & 7) << 3);
  const int ksw1 = (kr1 * 64 + kc0) ^ ((kr0 & 7) << 3);  // kr1&7 == kr0&7
  const int vsw0 = (vr0 * 128 + vc0) ^ ((vr0 & 7) << 3);
  const int vsw1 = (vr1 * 128 + vc0) ^ ((vr1 & 7) << 3);
  const int mti = t & 127;

  bf16x8 gk0 = *(const bf16x8*)&Kbase[(size_t)kr0 * 1024 + kc0];
  bf16x8 gk1 = *(const bf16x8*)&Kbase[(size_t)kr1 * 1024 + kc0];
  bf16x8 gv0 = *(const bf16x8*)&Vbase[(size_t)vr0 * 2048 + vc0];
  bf16x8 gv1 = *(const bf16x8*)&Vbase[(size_t)vr1 * 2048 + vc0];
  int gm = mask[b * 2048 + mti];

  const f32x4 fz = {0.f, 0.f, 0.f, 0.f};
  f32x4 o[4];                 // O[q=quad*4+r][d=nt*16+l15], unnormalized
  float lsum = 0.f;           // per-lane partial row-sum for q=l15
#pragma unroll
  for (int i = 0; i < 4; ++i) o[i] = fz;

  for (int kt = 0; kt < 2048; kt += 128) {
    __syncthreads();                              // prev tile fully consumed
    *(bf16x8*)&Ks[ksw0] = gk0;                    // waits prefetch vmcnt here
    *(bf16x8*)&Ks[ksw1] = gk1;
    *(bf16x8*)&Vs[vsw0] = gv0;
    *(bf16x8*)&Vs[vsw1] = gv1;
    if (t < 128) Mf[t] = gm ? -__builtin_inff() : 0.f;
    __syncthreads();
    const int kn = (kt + 128) & 2047;             // wrap: in-bounds, unused on last
    gk0 = *(const bf16x8*)&Kbase[(size_t)(kn + kr0) * 1024 + kc0];
    gk1 = *(const bf16x8*)&Kbase[(size_t)(kn + kr1) * 1024 + kc0];
    gv0 = *(const bf16x8*)&Vbase[(size_t)vr0 * 2048 + kn + vc0];
    gv1 = *(const bf16x8*)&Vbase[(size_t)vr1 * 2048 + kn + vc0];
    gm  = mask[b * 2048 + kn + mti];

#pragma unroll
    for (int h2 = 0; h2 < 2; ++h2) {              // two 64-key half-phases
      // S^T = (K Q^T)*scale + bias -> p = exp2;  4 key-groups of 16
#pragma unroll
      for (int nt = 0; nt < 4; ++nt) {
        const int g = h2 * 4 + nt;
        const int krow = g * 16 + l15;
        bf16x8 k0 = *(const bf16x8*)&Ks[(krow * 64 + quad * 8) ^ swz];
        bf16x8 k1 = *(const bf16x8*)&Ks[(krow * 64 + 32 + quad * 8) ^ swz];
        f32x4 acc = MFMA_B16(k0, qf0, fz);        // swapped: A=K rows, B=Q rows
        acc = MFMA_B16(k1, qf1, acc);
        // lane holds S[key=g*16+quad*4+r][q=l15]; bias indexed by key
        const float4 bias4 = *(const float4*)&Mf[g * 16 + quad * 4];
        float p0 = exp2f(fmaf(acc[0], cs, bias4.x));
        float p1 = exp2f(fmaf(acc[1], cs, bias4.y));
        float p2 = exp2f(fmaf(acc[2], cs, bias4.z));
        float p3 = exp2f(fmaf(acc[3], cs, bias4.w));
        lsum += (p0 + p1) + (p2 + p3);
        u32x2 pp;
        pp.x = cvtpk(p0, p1);                     // keys g*16+quad*4+0, +1
        pp.y = cvtpk(p2, p3);                     // keys g*16+quad*4+2, +3
        *(u32x2*)&Pl[wave][(l15 * 64 + nt * 16 + quad * 4) ^ swz] = pp;
      }
      // O += P_half @ V_half (wave-private Pl, no barrier)
#pragma unroll
      for (int kcc = 0; kcc < 2; ++kcc) {
        const int kc = h2 * 2 + kcc;
        const bf16x8 pf =
            *(const bf16x8*)&Pl[wave][(l15 * 64 + kcc * 32 + quad * 8) ^ swz];
#pragma unroll
        for (int nt = 0; nt < 4; ++nt) {
          const bf16x8 vf = *(const bf16x8*)
              &Vs[((nt * 16 + l15) * 128 + kc * 32 + quad * 8) ^ swz];
          o[nt] = MFMA_B16(pf, vf, o[nt]);
        }
      }
    }
  }
  // row sums: reduce across quads -> every lane holds L[l15]
  lsum += __shfl_xor(lsum, 16);
  lsum += __shfl_xor(lsum, 32);
  u16* cp = ctx + (size_t)(b * 2048 + q0) * 1024 + h * 64;
#pragma unroll
  for (int r = 0; r < 4; ++r) {
    const float lrow = __shfl(lsum, quad * 4 + r);  // L[q=quad*4+r]
    const bool ok = lrow > 0.f;
    const float inv = ok ? 1.f / lrow : 0.f;
#pragma unroll
    for (int nt = 0; nt < 4; ++nt)
      cp[(quad * 4 + r) * 1024 + nt * 16 + l15] = f2bf(ok ? o[nt][r] * inv : 0.f);
  }
}

// ---------------- host launch ------------------------------------------------
extern "C" void kernel_launch(void* const* d_in, const int* in_sizes, int n_in,
                              void* d_out, int out_size, void* d_ws, size_t ws_size,
                              hipStream_t stream) {
  const float* q    = (const float*)d_in[0];
  const float* k    = (const float*)d_in[1];
  const float* v    = (const float*)d_in[2];
  const int*   mask = (const int*)d_in[3];
  const float* Wq = (const float*)d_in[4];  const float* bq = (const float*)d_in[5];
  const float* Wk = (const float*)d_in[6];  const float* bk = (const float*)d_in[7];
  const float* Wv = (const float*)d_in[8];  const float* bv = (const float*)d_in[9];
  const float* Wo = (const float*)d_in[10]; const float* bo = (const float*)d_in[11];

  char* ws = (char*)d_ws;                       // 16 MB
  u16*   Kp  = (u16*)(ws + ((size_t)0 << 20));  // [4096][1024] bf16
  u16*   Vt  = (u16*)(ws + ((size_t)8 << 20));  // [32][64][2048] bf16
  float* O32 = (float*)ws;                      // [4096][1024] fp32 (after attn)

  char* od = (char*)d_out;                      // 16 MB
  u16* ctx = (u16*)od;                          // [0,8MB): Qp then ctx in-place
  u16* WqT = (u16*)(od + ((size_t)8 << 20));
  u16* WkT = (u16*)(od + ((size_t)10 << 20));
  u16* WvT = (u16*)(od + ((size_t)12 << 20));
  u16* WoT = (u16*)(od + ((size_t)14 << 20));

  dim3 blk(256);
  prep_w<<<dim3(16, 16, 4), blk, 0, stream>>>(Wq, Wk, Wv, Wo, WqT, WkT, WvT, WoT);
  gemm_bias<4, 1, 3><<<dim3(32, 24), blk, 0, stream>>>(
      q, k, v, WqT, bq, bk, bv, (void*)ctx, (void*)Kp, (void*)Vt);
  attn_fused<<<dim3(16, 32), dim3(512), 0, stream>>>(ctx, Kp, Vt, mask, ctx);
  gemm_bias<2, 0, 2><<<dim3(64, 8), blk, 0, stream>>>(
      ctx, nullptr, nullptr, WoT, bo, nullptr, nullptr, (void*)O32, nullptr, nullptr);
  hipMemcpyAsync(d_out, O32, (size_t)out_size * sizeof(float),
                 hipMemcpyDeviceToDevice, stream);
}